// Round 11
// baseline (215.596 us; speedup 1.0000x reference)
//
#include <hip/hip_runtime.h>
#include <math.h>

#define BB 8
#define MM 2048
#define NNP 2048
#define THR2 0.25f
#define NITER 10
#define NPART 17
#define TPB 1024
#define WPB 16                  // waves per block (8 pairs)
#define BPB 32                  // blocks per batch
#define GRIDB (BB * BPB)        // 256
#define TM 8                    // source points per wave-pair
#define HALF (NNP / 2)
#define STEPS (HALF / 64)       // 16 ds_read_b128 per wave per iteration
// ws layout: rtstore [BB][16] | endcnt [BB] uints (in float slot) | partials [NITER+1][BB][BPB][32]

__device__ inline float ld_acq_f(const float* p) {
    return __hip_atomic_load(p, __ATOMIC_ACQUIRE, __HIP_MEMORY_SCOPE_AGENT);
}

// ---------------- Jacobi fallback (only for degenerate H) ----------------
__device__ void kabsch3f(const float H[3][3], float R[3][3])
{
    float A[3][3];
    for (int i = 0; i < 3; ++i)
        for (int j = 0; j < 3; ++j) {
            float s = 0.0f;
            for (int k = 0; k < 3; ++k) s += H[k][i] * H[k][j];
            A[i][j] = s;
        }
    float V[3][3] = {{1,0,0},{0,1,0},{0,0,1}};
    const float nrm = A[0][0]*A[0][0] + A[1][1]*A[1][1] + A[2][2]*A[2][2] + 1e-30f;
    for (int sweep = 0; sweep < 8; ++sweep) {
        const float off = A[0][1]*A[0][1] + A[0][2]*A[0][2] + A[1][2]*A[1][2];
        if (off < 1e-14f * nrm) break;
        for (int pi = 0; pi < 3; ++pi) {
            const int p = (pi == 2) ? 1 : 0;
            const int q = (pi == 0) ? 1 : 2;
            const float apq = A[p][q];
            if (apq == 0.0f) continue;
            const float theta = (A[q][q] - A[p][p]) / (2.0f * apq);
            const float t = ((theta >= 0.0f) ? 1.0f : -1.0f) / (fabsf(theta) + sqrtf(theta * theta + 1.0f));
            const float c = 1.0f / sqrtf(t * t + 1.0f);
            const float s = t * c;
            const float app = A[p][p], aqq = A[q][q];
            A[p][p] = app - t * apq;
            A[q][q] = aqq + t * apq;
            A[p][q] = 0.0f; A[q][p] = 0.0f;
            const int r = 3 - p - q;
            const float arp = A[r][p], arq = A[r][q];
            A[r][p] = c * arp - s * arq; A[p][r] = A[r][p];
            A[r][q] = s * arp + c * arq; A[q][r] = A[r][q];
            for (int rr = 0; rr < 3; ++rr) {
                const float vrp = V[rr][p], vrq = V[rr][q];
                V[rr][p] = c * vrp - s * vrq;
                V[rr][q] = s * vrp + c * vrq;
            }
        }
    }
    float lam[3] = {A[0][0], A[1][1], A[2][2]};
    int ord[3] = {0, 1, 2};
    for (int i = 0; i < 2; ++i)
        for (int j = i + 1; j < 3; ++j)
            if (lam[ord[j]] > lam[ord[i]]) { const int tmp = ord[i]; ord[i] = ord[j]; ord[j] = tmp; }
    float Vs[3][3], U[3][3];
    for (int k = 0; k < 3; ++k) {
        const int c0 = ord[k];
        const float sk = sqrtf(fmaxf(lam[c0], 0.0f));
        const float inv = (sk > 1e-12f) ? 1.0f / sk : 0.0f;
        for (int i = 0; i < 3; ++i) {
            Vs[i][k] = V[i][c0];
            U[i][k] = (H[i][0] * V[0][c0] + H[i][1] * V[1][c0] + H[i][2] * V[2][c0]) * inv;
        }
    }
    const float detH = H[0][0] * (H[1][1] * H[2][2] - H[1][2] * H[2][1])
                     - H[0][1] * (H[1][0] * H[2][2] - H[1][2] * H[2][0])
                     + H[0][2] * (H[1][0] * H[2][1] - H[1][1] * H[2][0]);
    const float d = (detH < 0.0f) ? -1.0f : 1.0f;
    for (int i = 0; i < 3; ++i)
        for (int j = 0; j < 3; ++j)
            R[i][j] = Vs[i][0] * U[j][0] + Vs[i][1] * U[j][1] + d * Vs[i][2] * U[j][2];
}

// ---------------- corr: redundant Kabsch (Newton polar) + wave-pair scan ----------------
__global__ __launch_bounds__(TPB, 4) void corr_kernel(
    const int it,
    const float* __restrict__ pc_src,
    const float* __restrict__ pc_dest,
    const float* __restrict__ init_R,
    const float* __restrict__ init_t,
    float* __restrict__ rtstore,        // [BB][16]
    unsigned* __restrict__ endcnt,      // [BB]
    float* __restrict__ partials,       // [NITER+1][BB][BPB][32]
    float* __restrict__ out)
{
    const int blk = blockIdx.x;
    const int b = blk / BPB;
    const int cblk = blk % BPB;
    const int tid = threadIdx.x;
    const int wid = tid >> 6;
    const int lane = tid & 63;
    const int pairid = wid >> 1;        // 0..7
    const int half = wid & 1;

    __shared__ float4 ds[NNP];          // 32 KB dest: (x,y,z, valid? |d|^2 : INF)
    __shared__ float sred[BPB * 32];    // prev-iteration partial rows (4 KB)
    __shared__ float sminV[WPB][TM];
    __shared__ int   sminI[WPB][TM];
    __shared__ float smom[WPB / 2][NPART];
    __shared__ float Sfin[NPART];
    __shared__ float Rt[12];

    // ---- stage raw dest -> packed LDS (3 coalesced row reads, validity folded) ----
    const float dx0 = pc_dest[(b * 3 + 0) * NNP + tid];
    const float dy0 = pc_dest[(b * 3 + 1) * NNP + tid];
    const float dz0 = pc_dest[(b * 3 + 2) * NNP + tid];
    const float dx1 = pc_dest[(b * 3 + 0) * NNP + tid + TPB];
    const float dy1 = pc_dest[(b * 3 + 1) * NNP + tid + TPB];
    const float dz1 = pc_dest[(b * 3 + 2) * NNP + tid + TPB];
    const bool v0 = (dx0 != 0.0f) && (dy0 != 0.0f) && (dz0 != 0.0f);
    const bool v1 = (dx1 != 0.0f) && (dy1 != 0.0f) && (dz1 != 0.0f);
    ds[tid]       = make_float4(dx0, dy0, dz0, v0 ? dx0*dx0 + dy0*dy0 + dz0*dz0 : INFINITY);
    ds[tid + TPB] = make_float4(dx1, dy1, dz1, v1 ? dx1*dx1 + dy1*dy1 + dz1*dz1 : INFINITY);

    // ---- prev partials (visible across kernel boundary) / init R,t; zero end counter ----
    if (it > 0) {
        sred[tid] = partials[(size_t)((it - 1) * BB + b) * (BPB * 32) + tid];
    } else {
        if (tid < 9) Rt[tid] = init_R[b * 9 + tid];
        if (tid < 3) Rt[9 + tid] = init_t[b * 3 + tid];
        if (cblk == 0 && tid == 0) endcnt[b] = 0u;   // 10 boundaries before use at it==NITER
    }
    const float av = __syncthreads_or((int)(v0 || v1)) ? 1.0f : 0.0f;

    if (it > 0) {
        if (tid < NPART) {
            float s = 0.0f;
            #pragma unroll
            for (int c = 0; c < BPB; ++c) s += sred[c * 32 + tid];
            Sfin[tid] = s;
        }
        __syncthreads();
        // ---- redundant per-block Kabsch (identical arithmetic -> deterministic) ----
        if (tid == 0) {
            const float wsum = Sfin[0];
            if (wsum >= 0.5f) {
                const float safe = fmaxf(wsum, 1.0f);
                const float inv = 1.0f / safe;
                float mup[3], muq[3];
                #pragma unroll
                for (int i = 0; i < 3; ++i) { mup[i] = Sfin[1 + i] * inv; muq[i] = Sfin[4 + i] * inv; }
                float H[9];
                #pragma unroll
                for (int i = 0; i < 3; ++i)
                    #pragma unroll
                    for (int j = 0; j < 3; ++j)
                        H[i * 3 + j] = (Sfin[7 + i * 3 + j] * inv) - mup[i] * muq[j];
                const float detH = H[0] * (H[4]*H[8] - H[5]*H[7])
                                 - H[1] * (H[3]*H[8] - H[5]*H[6])
                                 + H[2] * (H[3]*H[7] - H[4]*H[6]);
                float R[9];
                if (detH > 1e-12f) {
                    // Kabsch R (det>0) == polar factor of H^T; Newton: X <- 0.5*(X + cof(X)/det(X))
                    float X[9] = {H[0], H[3], H[6], H[1], H[4], H[7], H[2], H[5], H[8]};
                    const float mu = 1.0f / cbrtf(detH);
                    #pragma unroll
                    for (int k = 0; k < 9; ++k) X[k] *= mu;
                    #pragma unroll
                    for (int itn = 0; itn < 6; ++itn) {
                        const float C0 = X[4]*X[8] - X[5]*X[7];
                        const float C1 = X[5]*X[6] - X[3]*X[8];
                        const float C2 = X[3]*X[7] - X[4]*X[6];
                        const float C3 = X[2]*X[7] - X[1]*X[8];
                        const float C4 = X[0]*X[8] - X[2]*X[6];
                        const float C5 = X[1]*X[6] - X[0]*X[7];
                        const float C6 = X[1]*X[5] - X[2]*X[4];
                        const float C7 = X[2]*X[3] - X[0]*X[5];
                        const float C8 = X[0]*X[4] - X[1]*X[3];
                        const float det = X[0]*C0 + X[1]*C1 + X[2]*C2;
                        const float h = 0.5f / det;
                        X[0] = 0.5f*X[0] + h*C0; X[1] = 0.5f*X[1] + h*C1; X[2] = 0.5f*X[2] + h*C2;
                        X[3] = 0.5f*X[3] + h*C3; X[4] = 0.5f*X[4] + h*C4; X[5] = 0.5f*X[5] + h*C5;
                        X[6] = 0.5f*X[6] + h*C6; X[7] = 0.5f*X[7] + h*C7; X[8] = 0.5f*X[8] + h*C8;
                    }
                    #pragma unroll
                    for (int k = 0; k < 9; ++k) R[k] = X[k];
                } else {
                    float H33[3][3], R33[3][3];
                    #pragma unroll
                    for (int i = 0; i < 3; ++i)
                        #pragma unroll
                        for (int j = 0; j < 3; ++j) H33[i][j] = H[i * 3 + j];
                    kabsch3f(H33, R33);
                    #pragma unroll
                    for (int i = 0; i < 3; ++i)
                        #pragma unroll
                        for (int j = 0; j < 3; ++j) R[i * 3 + j] = R33[i][j];
                }
                #pragma unroll
                for (int k = 0; k < 9; ++k) Rt[k] = R[k];
                #pragma unroll
                for (int i = 0; i < 3; ++i)
                    Rt[9 + i] = muq[i] - (R[i*3+0] * mup[0] + R[i*3+1] * mup[1] + R[i*3+2] * mup[2]);
            } else {
                // keep previous R/t (persisted by the previous launch)
                #pragma unroll
                for (int k = 0; k < 12; ++k) Rt[k] = rtstore[b * 16 + k];
            }
        }
        __syncthreads();
    }

    // ---- persist this launch's R/t; final-iteration R/t output ----
    if (cblk == 0 && tid < 12) {
        rtstore[b * 16 + tid] = Rt[tid];
        if (it == NITER) {
            if (tid < 9) out[b * 9 + tid] = Rt[tid];
            else out[72 + b * 3 + (tid - 9)] = Rt[tid];
        }
    }

    // ---- this pair's 8 source points (batch-0 source per reference) ----
    const int m0 = cblk * (WPB / 2 * TM) + pairid * TM;
    float sx[TM], sy[TM], sz[TM];
    #pragma unroll
    for (int t = 0; t < TM; ++t) {
        sx[t] = pc_src[0 * MM + m0 + t];
        sy[t] = pc_src[1 * MM + m0 + t];
        sz[t] = pc_src[2 * MM + m0 + t];
    }
    const int base = half * HALF;

    // ---- transform (argmin key drops per-m constant |p|^2) ----
    float nx[TM], ny[TM], nz[TM];
    #pragma unroll
    for (int t = 0; t < TM; ++t) {
        const float px = fmaf(Rt[0], sx[t], fmaf(Rt[1], sy[t], fmaf(Rt[2], sz[t], Rt[9])));
        const float py = fmaf(Rt[3], sx[t], fmaf(Rt[4], sy[t], fmaf(Rt[5], sz[t], Rt[10])));
        const float pz = fmaf(Rt[6], sx[t], fmaf(Rt[7], sy[t], fmaf(Rt[8], sz[t], Rt[11])));
        nx[t] = -2.0f * px; ny[t] = -2.0f * py; nz[t] = -2.0f * pz;
    }

    // ---- scan my half: 1 ds_read_b128 feeds 8 m-chains ----
    float best[TM]; int bidx[TM];
    #pragma unroll
    for (int t = 0; t < TM; ++t) { best[t] = INFINITY; bidx[t] = base + lane; }

    int j = base + lane;
    #pragma unroll 4
    for (int s = 0; s < STEPS; ++s, j += 64) {
        const float4 d = ds[j];
        #pragma unroll
        for (int t = 0; t < TM; ++t) {
            const float e = fmaf(nx[t], d.x, fmaf(ny[t], d.y, fmaf(nz[t], d.z, d.w)));
            if (e < best[t]) { best[t] = e; bidx[t] = j; }
        }
    }

    // ---- per-m cross-lane lex argmin (first-index tie-break) ----
    #pragma unroll
    for (int t = 0; t < TM; ++t) {
        float bv = best[t]; int bn = bidx[t];
        #pragma unroll
        for (int off = 32; off >= 1; off >>= 1) {
            const float ov = __shfl_xor(bv, off);
            const int on = __shfl_xor(bn, off);
            if (ov < bv || (ov == bv && on < bn)) { bv = ov; bn = on; }
        }
        best[t] = bv; bidx[t] = bn;
    }
    if (lane == 0) {
        #pragma unroll
        for (int t = 0; t < TM; ++t) { sminV[wid][t] = best[t]; sminI[wid][t] = bidx[t]; }
    }
    __syncthreads();

    // ---- even wave merges pair halves (tie -> even = lower index), moments ----
    // it==NITER needs only moments 0 and 16 (w, w*d2m) for the RMSE.
    if (!half) {
        float acc[NPART];
        #pragma unroll
        for (int k = 0; k < NPART; ++k) acc[k] = 0.0f;
        #pragma unroll
        for (int t = 0; t < TM; ++t) {
            float bv = best[t]; int bn = bidx[t];
            const float vO = sminV[wid + 1][t];
            const int iO = sminI[wid + 1][t];
            if (vO < bv) { bv = vO; bn = iO; }
            const float4 q = ds[bn];     // wave-uniform broadcast
            const float px = -0.5f * nx[t], py = -0.5f * ny[t], pz = -0.5f * nz[t];
            const float ex = px - q.x, ey = py - q.y, ez = pz - q.z;
            const float d2m = ex * ex + ey * ey + ez * ez;
            const float w = (d2m < THR2) ? av : 0.0f;
            acc[0] += w;
            acc[16] += w * d2m;
            if (it != NITER) {
                acc[1] += w * sx[t];  acc[2] += w * sy[t];  acc[3] += w * sz[t];
                acc[4] += w * q.x;    acc[5] += w * q.y;    acc[6] += w * q.z;
                acc[7]  += w * sx[t] * q.x; acc[8]  += w * sx[t] * q.y; acc[9]  += w * sx[t] * q.z;
                acc[10] += w * sy[t] * q.x; acc[11] += w * sy[t] * q.y; acc[12] += w * sy[t] * q.z;
                acc[13] += w * sz[t] * q.x; acc[14] += w * sz[t] * q.y; acc[15] += w * sz[t] * q.z;
            }
        }
        if (lane == 0) {
            #pragma unroll
            for (int k = 0; k < NPART; ++k) smom[pairid][k] = acc[k];
        }
    }
    __syncthreads();

    // ---- block moments -> this block's partial row ----
    if (tid < NPART) {
        float s = 0.0f;
        #pragma unroll
        for (int p = 0; p < WPB / 2; ++p) s += smom[p][tid];
        partials[(size_t)((it * BB + b) * BPB + cblk) * 32 + tid] = s;
    }

    // ---- it==NITER: single-shot last-block-done RMSE (replaces finalize launch) ----
    if (it == NITER) {
        __syncthreads();    // partial-row stores issued before the release RMW
        if (tid == 0) {
            const unsigned old = __hip_atomic_fetch_add(&endcnt[b], 1u,
                                    __ATOMIC_ACQ_REL, __HIP_MEMORY_SCOPE_AGENT);
            if (old == (unsigned)(BPB - 1)) {
                // last block of this batch: all 32 release-RMWs precede our acquire
                float w = 0.0f, wd = 0.0f;
                const float* rows = partials + (size_t)((NITER * BB + b) * BPB) * 32;
                for (int c = 0; c < BPB; ++c) {
                    w  += ld_acq_f(&rows[c * 32 + 0]);
                    wd += ld_acq_f(&rows[c * 32 + 16]);
                }
                const float safe = fmaxf(w, 1.0f);
                const float rmse = sqrtf(wd / safe);
                out[96 + b] = (w > 0.0f) ? rmse : __builtin_nanf("");
            }
        }
    }
}

extern "C" void kernel_launch(void* const* d_in, const int* in_sizes, int n_in,
                              void* d_out, int out_size, void* d_ws, size_t ws_size,
                              hipStream_t stream) {
    const float* pc_src  = (const float*)d_in[0];
    const float* pc_dest = (const float*)d_in[1];
    const float* init_R  = (const float*)d_in[2];
    const float* init_t  = (const float*)d_in[3];
    float* out = (float*)d_out;
    float* ws = (float*)d_ws;

    // ws layout (floats)
    float* rtstore    = ws;                            // BB*16
    unsigned* endcnt  = (unsigned*)(ws + BB * 16);     // BB
    float* partials   = ws + BB * 16 + BB;             // (NITER+1)*BB*BPB*32

    for (int it = 0; it <= NITER; ++it) {
        corr_kernel<<<GRIDB, TPB, 0, stream>>>(it, pc_src, pc_dest, init_R, init_t,
                                               rtstore, endcnt, partials, out);
    }
}

// Round 12
// 207.432 us; speedup vs baseline: 1.0394x; 1.0394x over previous
//
#include <hip/hip_runtime.h>
#include <math.h>

#define BB 8
#define MM 2048
#define NNP 2048
#define THR2 0.25f
#define NITER 10
#define NPART 17
#define TPB 1024
#define WPB 16                  // waves per block (8 pairs)
#define BPB 32                  // blocks per batch
#define GRIDB (BB * BPB)        // 256
#define TM 8                    // source points per wave-pair
#define HALF (NNP / 2)
#define STEPS (HALF / 64)       // 16 ds_read_b128 per wave per iteration
// ws layout: rtstore [BB][16] | endcnt [BB] uints | partials [NITER+1][BB][BPB][32]

__device__ inline float ld_acq_f(const float* p) {
    return __hip_atomic_load(p, __ATOMIC_ACQUIRE, __HIP_MEMORY_SCOPE_AGENT);
}

// ---------------- Jacobi fallback (only for degenerate H) ----------------
__device__ void kabsch3f(const float H[3][3], float R[3][3])
{
    float A[3][3];
    for (int i = 0; i < 3; ++i)
        for (int j = 0; j < 3; ++j) {
            float s = 0.0f;
            for (int k = 0; k < 3; ++k) s += H[k][i] * H[k][j];
            A[i][j] = s;
        }
    float V[3][3] = {{1,0,0},{0,1,0},{0,0,1}};
    const float nrm = A[0][0]*A[0][0] + A[1][1]*A[1][1] + A[2][2]*A[2][2] + 1e-30f;
    for (int sweep = 0; sweep < 8; ++sweep) {
        const float off = A[0][1]*A[0][1] + A[0][2]*A[0][2] + A[1][2]*A[1][2];
        if (off < 1e-14f * nrm) break;
        for (int pi = 0; pi < 3; ++pi) {
            const int p = (pi == 2) ? 1 : 0;
            const int q = (pi == 0) ? 1 : 2;
            const float apq = A[p][q];
            if (apq == 0.0f) continue;
            const float theta = (A[q][q] - A[p][p]) / (2.0f * apq);
            const float t = ((theta >= 0.0f) ? 1.0f : -1.0f) / (fabsf(theta) + sqrtf(theta * theta + 1.0f));
            const float c = 1.0f / sqrtf(t * t + 1.0f);
            const float s = t * c;
            const float app = A[p][p], aqq = A[q][q];
            A[p][p] = app - t * apq;
            A[q][q] = aqq + t * apq;
            A[p][q] = 0.0f; A[q][p] = 0.0f;
            const int r = 3 - p - q;
            const float arp = A[r][p], arq = A[r][q];
            A[r][p] = c * arp - s * arq; A[p][r] = A[r][p];
            A[r][q] = s * arp + c * arq; A[q][r] = A[r][q];
            for (int rr = 0; rr < 3; ++rr) {
                const float vrp = V[rr][p], vrq = V[rr][q];
                V[rr][p] = c * vrp - s * vrq;
                V[rr][q] = s * vrp + c * vrq;
            }
        }
    }
    float lam[3] = {A[0][0], A[1][1], A[2][2]};
    int ord[3] = {0, 1, 2};
    for (int i = 0; i < 2; ++i)
        for (int j = i + 1; j < 3; ++j)
            if (lam[ord[j]] > lam[ord[i]]) { const int tmp = ord[i]; ord[i] = ord[j]; ord[j] = tmp; }
    float Vs[3][3], U[3][3];
    for (int k = 0; k < 3; ++k) {
        const int c0 = ord[k];
        const float sk = sqrtf(fmaxf(lam[c0], 0.0f));
        const float inv = (sk > 1e-12f) ? 1.0f / sk : 0.0f;
        for (int i = 0; i < 3; ++i) {
            Vs[i][k] = V[i][c0];
            U[i][k] = (H[i][0] * V[0][c0] + H[i][1] * V[1][c0] + H[i][2] * V[2][c0]) * inv;
        }
    }
    const float detH = H[0][0] * (H[1][1] * H[2][2] - H[1][2] * H[2][1])
                     - H[0][1] * (H[1][0] * H[2][2] - H[1][2] * H[2][0])
                     + H[0][2] * (H[1][0] * H[2][1] - H[1][1] * H[2][0]);
    const float d = (detH < 0.0f) ? -1.0f : 1.0f;
    for (int i = 0; i < 3; ++i)
        for (int j = 0; j < 3; ++j)
            R[i][j] = Vs[i][0] * U[j][0] + Vs[i][1] * U[j][1] + d * Vs[i][2] * U[j][2];
}

// ---------------- corr: redundant Kabsch (Newton polar) + wave-pair scan ----------------
// LAST=0: it=0..9 (all 17 moments, identical to R10 hot path)
// LAST=1: it=10 (2 RMSE moments + fused last-block-done RMSE; no further Kabsch consumer)
template<int LAST>
__global__ __launch_bounds__(TPB, 4) void corr_kernel(
    const int it,
    const float* __restrict__ pc_src,
    const float* __restrict__ pc_dest,
    const float* __restrict__ init_R,
    const float* __restrict__ init_t,
    float* __restrict__ rtstore,        // [BB][16]
    unsigned* __restrict__ endcnt,      // [BB]
    float* __restrict__ partials,       // [NITER+1][BB][BPB][32]
    float* __restrict__ out)
{
    const int blk = blockIdx.x;
    const int b = blk / BPB;
    const int cblk = blk % BPB;
    const int tid = threadIdx.x;
    const int wid = tid >> 6;
    const int lane = tid & 63;
    const int pairid = wid >> 1;        // 0..7
    const int half = wid & 1;

    __shared__ float4 ds[NNP];          // 32 KB dest: (x,y,z, valid? |d|^2 : INF)
    __shared__ float sred[BPB * 32];    // prev-iteration partial rows (4 KB)
    __shared__ float sminV[WPB][TM];
    __shared__ int   sminI[WPB][TM];
    __shared__ float smom[WPB / 2][NPART];
    __shared__ float Sfin[NPART];
    __shared__ float Rt[12];

    // ---- stage raw dest -> packed LDS (3 coalesced row reads, validity folded) ----
    const float dx0 = pc_dest[(b * 3 + 0) * NNP + tid];
    const float dy0 = pc_dest[(b * 3 + 1) * NNP + tid];
    const float dz0 = pc_dest[(b * 3 + 2) * NNP + tid];
    const float dx1 = pc_dest[(b * 3 + 0) * NNP + tid + TPB];
    const float dy1 = pc_dest[(b * 3 + 1) * NNP + tid + TPB];
    const float dz1 = pc_dest[(b * 3 + 2) * NNP + tid + TPB];
    const bool v0 = (dx0 != 0.0f) && (dy0 != 0.0f) && (dz0 != 0.0f);
    const bool v1 = (dx1 != 0.0f) && (dy1 != 0.0f) && (dz1 != 0.0f);
    ds[tid]       = make_float4(dx0, dy0, dz0, v0 ? dx0*dx0 + dy0*dy0 + dz0*dz0 : INFINITY);
    ds[tid + TPB] = make_float4(dx1, dy1, dz1, v1 ? dx1*dx1 + dy1*dy1 + dz1*dz1 : INFINITY);

    // ---- prev partials (visible across kernel boundary) / init R,t; zero end counter ----
    if (it > 0) {
        sred[tid] = partials[(size_t)((it - 1) * BB + b) * (BPB * 32) + tid];
    } else {
        if (tid < 9) Rt[tid] = init_R[b * 9 + tid];
        if (tid < 3) Rt[9 + tid] = init_t[b * 3 + tid];
        if (cblk == 0 && tid == 0) endcnt[b] = 0u;   // 10 boundaries before use at it==NITER
    }
    const float av = __syncthreads_or((int)(v0 || v1)) ? 1.0f : 0.0f;

    if (it > 0) {
        if (tid < NPART) {
            float s = 0.0f;
            #pragma unroll
            for (int c = 0; c < BPB; ++c) s += sred[c * 32 + tid];
            Sfin[tid] = s;
        }
        __syncthreads();
        // ---- redundant per-block Kabsch (identical arithmetic -> deterministic) ----
        if (tid == 0) {
            const float wsum = Sfin[0];
            if (wsum >= 0.5f) {
                const float safe = fmaxf(wsum, 1.0f);
                const float inv = 1.0f / safe;
                float mup[3], muq[3];
                #pragma unroll
                for (int i = 0; i < 3; ++i) { mup[i] = Sfin[1 + i] * inv; muq[i] = Sfin[4 + i] * inv; }
                float H[9];
                #pragma unroll
                for (int i = 0; i < 3; ++i)
                    #pragma unroll
                    for (int j = 0; j < 3; ++j)
                        H[i * 3 + j] = (Sfin[7 + i * 3 + j] * inv) - mup[i] * muq[j];
                const float detH = H[0] * (H[4]*H[8] - H[5]*H[7])
                                 - H[1] * (H[3]*H[8] - H[5]*H[6])
                                 + H[2] * (H[3]*H[7] - H[4]*H[6]);
                float R[9];
                if (detH > 1e-12f) {
                    // Kabsch R (det>0) == polar factor of H^T; Newton: X <- 0.5*(X + cof(X)/det(X))
                    float X[9] = {H[0], H[3], H[6], H[1], H[4], H[7], H[2], H[5], H[8]};
                    const float mu = 1.0f / cbrtf(detH);
                    #pragma unroll
                    for (int k = 0; k < 9; ++k) X[k] *= mu;
                    #pragma unroll
                    for (int itn = 0; itn < 6; ++itn) {
                        const float C0 = X[4]*X[8] - X[5]*X[7];
                        const float C1 = X[5]*X[6] - X[3]*X[8];
                        const float C2 = X[3]*X[7] - X[4]*X[6];
                        const float C3 = X[2]*X[7] - X[1]*X[8];
                        const float C4 = X[0]*X[8] - X[2]*X[6];
                        const float C5 = X[1]*X[6] - X[0]*X[7];
                        const float C6 = X[1]*X[5] - X[2]*X[4];
                        const float C7 = X[2]*X[3] - X[0]*X[5];
                        const float C8 = X[0]*X[4] - X[1]*X[3];
                        const float det = X[0]*C0 + X[1]*C1 + X[2]*C2;
                        const float h = 0.5f / det;
                        X[0] = 0.5f*X[0] + h*C0; X[1] = 0.5f*X[1] + h*C1; X[2] = 0.5f*X[2] + h*C2;
                        X[3] = 0.5f*X[3] + h*C3; X[4] = 0.5f*X[4] + h*C4; X[5] = 0.5f*X[5] + h*C5;
                        X[6] = 0.5f*X[6] + h*C6; X[7] = 0.5f*X[7] + h*C7; X[8] = 0.5f*X[8] + h*C8;
                    }
                    #pragma unroll
                    for (int k = 0; k < 9; ++k) R[k] = X[k];
                } else {
                    float H33[3][3], R33[3][3];
                    #pragma unroll
                    for (int i = 0; i < 3; ++i)
                        #pragma unroll
                        for (int j = 0; j < 3; ++j) H33[i][j] = H[i * 3 + j];
                    kabsch3f(H33, R33);
                    #pragma unroll
                    for (int i = 0; i < 3; ++i)
                        #pragma unroll
                        for (int j = 0; j < 3; ++j) R[i * 3 + j] = R33[i][j];
                }
                #pragma unroll
                for (int k = 0; k < 9; ++k) Rt[k] = R[k];
                #pragma unroll
                for (int i = 0; i < 3; ++i)
                    Rt[9 + i] = muq[i] - (R[i*3+0] * mup[0] + R[i*3+1] * mup[1] + R[i*3+2] * mup[2]);
            } else {
                // keep previous R/t (persisted by the previous launch)
                #pragma unroll
                for (int k = 0; k < 12; ++k) Rt[k] = rtstore[b * 16 + k];
            }
        }
        __syncthreads();
    }

    // ---- persist this launch's R/t; final-iteration R/t output ----
    if (cblk == 0 && tid < 12) {
        if (!LAST) rtstore[b * 16 + tid] = Rt[tid];
        else {
            if (tid < 9) out[b * 9 + tid] = Rt[tid];
            else out[72 + b * 3 + (tid - 9)] = Rt[tid];
        }
    }

    // ---- this pair's 8 source points (batch-0 source per reference) ----
    const int m0 = cblk * (WPB / 2 * TM) + pairid * TM;
    float sx[TM], sy[TM], sz[TM];
    #pragma unroll
    for (int t = 0; t < TM; ++t) {
        sx[t] = pc_src[0 * MM + m0 + t];
        sy[t] = pc_src[1 * MM + m0 + t];
        sz[t] = pc_src[2 * MM + m0 + t];
    }
    const int base = half * HALF;

    // ---- transform (argmin key drops per-m constant |p|^2) ----
    float nx[TM], ny[TM], nz[TM];
    #pragma unroll
    for (int t = 0; t < TM; ++t) {
        const float px = fmaf(Rt[0], sx[t], fmaf(Rt[1], sy[t], fmaf(Rt[2], sz[t], Rt[9])));
        const float py = fmaf(Rt[3], sx[t], fmaf(Rt[4], sy[t], fmaf(Rt[5], sz[t], Rt[10])));
        const float pz = fmaf(Rt[6], sx[t], fmaf(Rt[7], sy[t], fmaf(Rt[8], sz[t], Rt[11])));
        nx[t] = -2.0f * px; ny[t] = -2.0f * py; nz[t] = -2.0f * pz;
    }

    // ---- scan my half: 1 ds_read_b128 feeds 8 m-chains ----
    float best[TM]; int bidx[TM];
    #pragma unroll
    for (int t = 0; t < TM; ++t) { best[t] = INFINITY; bidx[t] = base + lane; }

    int j = base + lane;
    #pragma unroll 4
    for (int s = 0; s < STEPS; ++s, j += 64) {
        const float4 d = ds[j];
        #pragma unroll
        for (int t = 0; t < TM; ++t) {
            const float e = fmaf(nx[t], d.x, fmaf(ny[t], d.y, fmaf(nz[t], d.z, d.w)));
            if (e < best[t]) { best[t] = e; bidx[t] = j; }
        }
    }

    // ---- per-m cross-lane lex argmin (first-index tie-break) ----
    #pragma unroll
    for (int t = 0; t < TM; ++t) {
        float bv = best[t]; int bn = bidx[t];
        #pragma unroll
        for (int off = 32; off >= 1; off >>= 1) {
            const float ov = __shfl_xor(bv, off);
            const int on = __shfl_xor(bn, off);
            if (ov < bv || (ov == bv && on < bn)) { bv = ov; bn = on; }
        }
        best[t] = bv; bidx[t] = bn;
    }
    if (lane == 0) {
        #pragma unroll
        for (int t = 0; t < TM; ++t) { sminV[wid][t] = best[t]; sminI[wid][t] = bidx[t]; }
    }
    __syncthreads();

    // ---- even wave merges pair halves (tie -> even = lower index), moments ----
    if (!half) {
        float acc[NPART];
        #pragma unroll
        for (int k = 0; k < NPART; ++k) acc[k] = 0.0f;
        #pragma unroll
        for (int t = 0; t < TM; ++t) {
            float bv = best[t]; int bn = bidx[t];
            const float vO = sminV[wid + 1][t];
            const int iO = sminI[wid + 1][t];
            if (vO < bv) { bv = vO; bn = iO; }
            const float4 q = ds[bn];     // wave-uniform broadcast
            const float px = -0.5f * nx[t], py = -0.5f * ny[t], pz = -0.5f * nz[t];
            const float ex = px - q.x, ey = py - q.y, ez = pz - q.z;
            const float d2m = ex * ex + ey * ey + ez * ez;
            const float w = (d2m < THR2) ? av : 0.0f;
            acc[0] += w;
            acc[16] += w * d2m;
            if (!LAST) {    // compile-time: full moment set only when a Kabsch consumer exists
                acc[1] += w * sx[t];  acc[2] += w * sy[t];  acc[3] += w * sz[t];
                acc[4] += w * q.x;    acc[5] += w * q.y;    acc[6] += w * q.z;
                acc[7]  += w * sx[t] * q.x; acc[8]  += w * sx[t] * q.y; acc[9]  += w * sx[t] * q.z;
                acc[10] += w * sy[t] * q.x; acc[11] += w * sy[t] * q.y; acc[12] += w * sy[t] * q.z;
                acc[13] += w * sz[t] * q.x; acc[14] += w * sz[t] * q.y; acc[15] += w * sz[t] * q.z;
            }
        }
        if (lane == 0) {
            #pragma unroll
            for (int k = 0; k < NPART; ++k) smom[pairid][k] = acc[k];
        }
    }
    __syncthreads();

    // ---- block moments -> this block's partial row ----
    if (tid < NPART) {
        float s = 0.0f;
        #pragma unroll
        for (int p = 0; p < WPB / 2; ++p) s += smom[p][tid];
        partials[(size_t)((it * BB + b) * BPB + cblk) * 32 + tid] = s;
    }

    // ---- LAST: single-shot last-block-done RMSE (replaces finalize launch) ----
    if (LAST) {
        __syncthreads();    // partial-row stores complete before the release RMW
        if (wid == 0) {
            unsigned old = 0;
            if (lane == 0)
                old = __hip_atomic_fetch_add(&endcnt[b], 1u,
                                             __ATOMIC_ACQ_REL, __HIP_MEMORY_SCOPE_AGENT);
            old = __shfl(old, 0);
            if (old == (unsigned)(BPB - 1)) {
                // last block of this batch: all 32 releases precede our acquires
                const float* rows = partials + (size_t)((NITER * BB + b) * BPB) * 32;
                float w = 0.0f, wd = 0.0f;
                if (lane < BPB) {
                    w  = ld_acq_f(&rows[lane * 32 + 0]);
                    wd = ld_acq_f(&rows[lane * 32 + 16]);
                }
                #pragma unroll
                for (int off = 16; off >= 1; off >>= 1) {
                    w += __shfl_xor(w, off);
                    wd += __shfl_xor(wd, off);
                }
                if (lane == 0) {
                    const float safe = fmaxf(w, 1.0f);
                    const float rmse = sqrtf(wd / safe);
                    out[96 + b] = (w > 0.0f) ? rmse : __builtin_nanf("");
                }
            }
        }
    }
}

extern "C" void kernel_launch(void* const* d_in, const int* in_sizes, int n_in,
                              void* d_out, int out_size, void* d_ws, size_t ws_size,
                              hipStream_t stream) {
    const float* pc_src  = (const float*)d_in[0];
    const float* pc_dest = (const float*)d_in[1];
    const float* init_R  = (const float*)d_in[2];
    const float* init_t  = (const float*)d_in[3];
    float* out = (float*)d_out;
    float* ws = (float*)d_ws;

    // ws layout (floats)
    float* rtstore    = ws;                            // BB*16
    unsigned* endcnt  = (unsigned*)(ws + BB * 16);     // BB
    float* partials   = ws + BB * 16 + BB;             // (NITER+1)*BB*BPB*32

    for (int it = 0; it < NITER; ++it) {
        corr_kernel<0><<<GRIDB, TPB, 0, stream>>>(it, pc_src, pc_dest, init_R, init_t,
                                                  rtstore, endcnt, partials, out);
    }
    corr_kernel<1><<<GRIDB, TPB, 0, stream>>>(NITER, pc_src, pc_dest, init_R, init_t,
                                              rtstore, endcnt, partials, out);
}